// Round 5
// baseline (438.775 us; speedup 1.0000x reference)
//
#include <hip/hip_runtime.h>
#include <hip/hip_bf16.h>

#define NV 100000
#define ND 64
#define NB 4096
#define NL 200

typedef __bf16 bf16_t;
typedef __bf16 bf16x8 __attribute__((ext_vector_type(8)));
typedef float  f32x4  __attribute__((ext_vector_type(4)));

// f32 table -> bf16 table in ws. 800000 threads x 8 elems = 6.4M exactly.
__global__ __launch_bounds__(256)
void din_cvt(const float* __restrict__ emb, bf16_t* __restrict__ embh)
{
    const long base = ((long)blockIdx.x * 256 + threadIdx.x) * 8;
    f32x4 a0 = *(const f32x4*)(emb + base);
    f32x4 a1 = *(const f32x4*)(emb + base + 4);
    bf16x8 o;
    #pragma unroll
    for (int i = 0; i < 4; ++i) { o[i] = (bf16_t)a0[i]; o[i + 4] = (bf16_t)a1[i]; }
    *(bf16x8*)(embh + base) = o;
}

// One WAVE per batch item. No LDS, no __syncthreads: pure wave-level dataflow.
// Online softmax (flash-style) keeps the pooled accumulator in registers.
template <bool BT>
__global__ __launch_bounds__(256, 4)
void din_kernel1(const int* __restrict__ item_ids,
                 const int* __restrict__ history,
                 const int* __restrict__ hist_len,
                 const float* __restrict__ emb,
                 const bf16_t* __restrict__ embh,
                 const float* __restrict__ aW1,
                 const float* __restrict__ ab1,
                 const float* __restrict__ aW2,
                 float* __restrict__ comb_ws)
{
    const int tid  = threadIdx.x;
    const int wave = tid >> 6, lane = tid & 63;
    const int b    = blockIdx.x * 4 + wave;
    const int col  = lane & 15, quad = lane >> 4;

    const int item = item_ids[b];
    const int len  = hist_len[b];                 // [1, 200]
    const float* trow = emb + (long)item * ND;

    // ---- all 13 tile indices up-front (L2-hot, contiguous 64B/tile) ----
    int idxs[13];
    #pragma unroll
    for (int mt = 0; mt < 13; ++mt) {
        int l = mt * 16 + col;
        idxs[mt] = history[b * NL + (l < NL ? l : NL - 1)];
    }

    // ---- target slices this lane needs ----
    f32x4 tA0a = *(const f32x4*)(trow + quad * 8);          // t[quad*8 .. +4)
    f32x4 tA0b = *(const f32x4*)(trow + quad * 8 + 4);
    f32x4 tA1a = *(const f32x4*)(trow + 32 + quad * 8);     // t[32+quad*8 ..)
    f32x4 tA1b = *(const f32x4*)(trow + 32 + quad * 8 + 4);
    f32x4 tc0  = *(const f32x4*)(trow + quad * 16);         // t[quad*16 .. +16)
    f32x4 tc1  = *(const f32x4*)(trow + quad * 16 + 4);
    f32x4 tc2  = *(const f32x4*)(trow + quad * 16 + 8);
    f32x4 tc3  = *(const f32x4*)(trow + quad * 16 + 12);

    // ---- cb[nt] = ab1[n] + sum_k t[k]*aW1[64+k][n],  n = nt*16+col ----
    float cvals[4];
    {
        float part[4];
        #pragma unroll
        for (int nt = 0; nt < 4; ++nt) {
            const int n = nt * 16 + col;
            const float* pb = aW1 + (long)(64 + quad * 16) * 64 + n;
            float s = 0.f;
            #pragma unroll
            for (int j = 0; j < 16; ++j) {
                float tk = (j < 4) ? tc0[j] : (j < 8) ? tc1[j - 4]
                         : (j < 12) ? tc2[j - 8] : tc3[j - 12];
                s += tk * pb[j * 64];
            }
            part[nt] = s;
        }
        #pragma unroll
        for (int nt = 0; nt < 4; ++nt) {
            part[nt] += __shfl_xor(part[nt], 16, 64);
            part[nt] += __shfl_xor(part[nt], 32, 64);
            cvals[nt] = part[nt] + ab1[nt * 16 + col];
        }
    }

    // ---- bfrag[nt][kb][j] = bf16( aW1[k][n] + t[k]*aW1[128+k][n] ), k = kb*32+quad*8+j ----
    bf16x8 bfrag[4][2];
    #pragma unroll
    for (int kb = 0; kb < 2; ++kb) {
        #pragma unroll
        for (int nt = 0; nt < 4; ++nt) {
            const int n = nt * 16 + col;
            const float* pa = aW1 + (long)(kb * 32 + quad * 8) * 64 + n;
            const float* pc = pa + 128 * 64;
            bf16x8 w;
            #pragma unroll
            for (int j = 0; j < 8; ++j) {
                float tk = (kb == 0) ? ((j < 4) ? tA0a[j] : tA0b[j - 4])
                                     : ((j < 4) ? tA1a[j] : tA1b[j - 4]);
                w[j] = (bf16_t)(pa[j * 64] + tk * pc[j * 64]);
            }
            bfrag[nt][kb] = w;
        }
    }
    float a2vals[4];
    #pragma unroll
    for (int nt = 0; nt < 4; ++nt) a2vals[nt] = aW2[nt * 16 + col];

    // ---- row gather: lane (col,quad) holds row=col's dims [quad*8..+8) and [32+quad*8..+8) ----
    auto load_rows = [&](int mt, bf16x8& o0, bf16x8& o1) {
        if constexpr (BT) {
            const bf16_t* s = embh + (long)idxs[mt] * ND + quad * 8;
            o0 = *(const bf16x8*)(s);
            o1 = *(const bf16x8*)(s + 32);
        } else {
            const float* s = emb + (long)idxs[mt] * ND + quad * 8;
            f32x4 a0 = *(const f32x4*)(s),      a1 = *(const f32x4*)(s + 4);
            f32x4 a2 = *(const f32x4*)(s + 32), a3 = *(const f32x4*)(s + 36);
            #pragma unroll
            for (int i = 0; i < 4; ++i) {
                o0[i] = (bf16_t)a0[i]; o0[i + 4] = (bf16_t)a1[i];
                o1[i] = (bf16_t)a2[i]; o1[i + 4] = (bf16_t)a3[i];
            }
        }
    };

    // ---- online-softmax state ----
    float mrun = -1e30f, Z = 0.f;
    float po0[8], po1[8];
    #pragma unroll
    for (int j = 0; j < 8; ++j) { po0[j] = 0.f; po1[j] = 0.f; }

    bf16x8 naf0, naf1;
    load_rows(0, naf0, naf1);

    #pragma unroll
    for (int mt = 0; mt < 13; ++mt) {
        bf16x8 af0 = naf0, af1 = naf1;
        if (mt + 1 < 13) load_rows(mt + 1, naf0, naf1);   // prefetch next tile

        const bool valid = (mt * 16 + col) < len;          // l>=200 => invalid too
        if (!valid) { af0 = (bf16x8)(bf16_t)0.f; af1 = (bf16x8)(bf16_t)0.f; }

        // scores: sc[i] = aW2 . relu(h_row . Wb + cb),  row = mt*16 + quad*4 + i
        float sc[4] = {0.f, 0.f, 0.f, 0.f};
        #pragma unroll
        for (int nt = 0; nt < 4; ++nt) {
            f32x4 acc = {0.f, 0.f, 0.f, 0.f};
            acc = __builtin_amdgcn_mfma_f32_16x16x32_bf16(af0, bfrag[nt][0], acc, 0, 0, 0);
            acc = __builtin_amdgcn_mfma_f32_16x16x32_bf16(af1, bfrag[nt][1], acc, 0, 0, 0);
            #pragma unroll
            for (int i = 0; i < 4; ++i) {
                float h = acc[i] + cvals[nt];
                h = h > 0.f ? h : 0.f;
                sc[i] += h * a2vals[nt];
            }
        }
        #pragma unroll
        for (int off = 1; off < 16; off <<= 1)
            #pragma unroll
            for (int i = 0; i < 4; ++i) sc[i] += __shfl_xor(sc[i], off, 64);

        // rows >= 200 excluded from softmax entirely
        #pragma unroll
        for (int i = 0; i < 4; ++i)
            if (mt * 16 + quad * 4 + i >= NL) sc[i] = -1e30f;

        // tile max (over quads; cols identical)
        float tm = fmaxf(fmaxf(sc[0], sc[1]), fmaxf(sc[2], sc[3]));
        tm = fmaxf(tm, __shfl_xor(tm, 16, 64));
        tm = fmaxf(tm, __shfl_xor(tm, 32, 64));
        float mnew  = fmaxf(mrun, tm);
        float alpha = __expf(mrun - mnew);

        float e[4];
        #pragma unroll
        for (int i = 0; i < 4; ++i) e[i] = __expf(sc[i] - mnew);
        float zt = e[0] + e[1] + e[2] + e[3];
        zt += __shfl_xor(zt, 16, 64);
        zt += __shfl_xor(zt, 32, 64);
        Z = Z * alpha + zt;
        mrun = mnew;

        // weight for THIS lane's frag row (= row col): fetch e_{col} from quad col>>2
        float esel = (col & 2) ? ((col & 1) ? e[3] : e[2])
                               : ((col & 1) ? e[1] : e[0]);
        float p = __shfl(esel, (col >> 2) * 16 + col, 64);

        #pragma unroll
        for (int j = 0; j < 8; ++j) {
            po0[j] = po0[j] * alpha + p * (float)af0[j];
            po1[j] = po1[j] * alpha + p * (float)af1[j];
        }
    }

    // ---- finalize pooled: reduce over col lanes, normalize ----
    #pragma unroll
    for (int off = 1; off < 16; off <<= 1)
        #pragma unroll
        for (int j = 0; j < 8; ++j) {
            po0[j] += __shfl_xor(po0[j], off, 64);
            po1[j] += __shfl_xor(po1[j], off, 64);
        }
    const float invZ = 1.f / Z;
    #pragma unroll
    for (int j = 0; j < 8; ++j) { po0[j] *= invZ; po1[j] *= invZ; }

    // ---- comb = [tgt, pooled, pooled - tgt]; lane's dims: quad*8+j and 32+quad*8+j ----
    float* cw = comb_ws + (long)b * 192;
    if (col == 2) {        // tgt
        *(f32x4*)(cw + quad * 8)          = tA0a;
        *(f32x4*)(cw + quad * 8 + 4)      = tA0b;
        *(f32x4*)(cw + 32 + quad * 8)     = tA1a;
        *(f32x4*)(cw + 32 + quad * 8 + 4) = tA1b;
    } else if (col == 0) { // pooled
        f32x4 v0 = {po0[0], po0[1], po0[2], po0[3]};
        f32x4 v1 = {po0[4], po0[5], po0[6], po0[7]};
        f32x4 v2 = {po1[0], po1[1], po1[2], po1[3]};
        f32x4 v3 = {po1[4], po1[5], po1[6], po1[7]};
        *(f32x4*)(cw + 64 + quad * 8)          = v0;
        *(f32x4*)(cw + 64 + quad * 8 + 4)      = v1;
        *(f32x4*)(cw + 96 + quad * 8)          = v2;
        *(f32x4*)(cw + 96 + quad * 8 + 4)      = v3;
    } else if (col == 1) { // pooled - tgt
        f32x4 v0 = {po0[0] - tA0a[0], po0[1] - tA0a[1], po0[2] - tA0a[2], po0[3] - tA0a[3]};
        f32x4 v1 = {po0[4] - tA0b[0], po0[5] - tA0b[1], po0[6] - tA0b[2], po0[7] - tA0b[3]};
        f32x4 v2 = {po1[0] - tA1a[0], po1[1] - tA1a[1], po1[2] - tA1a[2], po1[3] - tA1a[3]};
        f32x4 v3 = {po1[4] - tA1b[0], po1[5] - tA1b[1], po1[6] - tA1b[2], po1[7] - tA1b[3]};
        *(f32x4*)(cw + 128 + quad * 8)          = v0;
        *(f32x4*)(cw + 128 + quad * 8 + 4)      = v1;
        *(f32x4*)(cw + 160 + quad * 8)          = v2;
        *(f32x4*)(cw + 160 + quad * 8 + 4)      = v3;
    }
}

__global__ __launch_bounds__(256)
void din_kernel2(const float* __restrict__ comb,
                 const float* __restrict__ fW1, const float* __restrict__ fb1,
                 const float* __restrict__ fW2, const float* __restrict__ fb2,
                 const float* __restrict__ fW3, const float* __restrict__ fb3,
                 float* __restrict__ out)
{
    __shared__ float combs[4 * 192];
    __shared__ float z1s[4 * 128];
    const int tid = threadIdx.x;
    const int rb  = blockIdx.x * 4;

    for (int i = tid; i < 4 * 192; i += 256) combs[i] = comb[(long)rb * 192 + i];
    __syncthreads();

    {
        const int j  = tid & 127;
        const int r0 = (tid >> 7) * 2, r1 = r0 + 1;
        float a0 = fb1[j], a1 = a0;
        #pragma unroll 4
        for (int i = 0; i < 192; ++i) {
            float w = fW1[i * 128 + j];
            a0 += combs[r0 * 192 + i] * w;
            a1 += combs[r1 * 192 + i] * w;
        }
        z1s[r0 * 128 + j] = fmaxf(a0, 0.f);
        z1s[r1 * 128 + j] = fmaxf(a1, 0.f);
    }
    __syncthreads();

    {
        const int j2 = tid & 63;
        const int r2 = tid >> 6;
        float acc = fb2[j2];
        #pragma unroll 4
        for (int i = 0; i < 128; ++i)
            acc += z1s[r2 * 128 + i] * fW2[i * 64 + j2];
        float s = fmaxf(acc, 0.f) * fW3[j2];
        #pragma unroll
        for (int off = 1; off < 64; off <<= 1) s += __shfl_xor(s, off, 64);
        if (j2 == 0) out[rb + r2] = 1.f / (1.f + __expf(-(s + fb3[0])));
    }
}

extern "C" void kernel_launch(void* const* d_in, const int* in_sizes, int n_in,
                              void* d_out, int out_size, void* d_ws, size_t ws_size,
                              hipStream_t stream) {
    const int*   item_ids = (const int*)d_in[0];
    const int*   history  = (const int*)d_in[1];
    const int*   hist_len = (const int*)d_in[2];
    const float* emb      = (const float*)d_in[3];
    const float* aW1      = (const float*)d_in[4];
    const float* ab1      = (const float*)d_in[5];
    const float* aW2      = (const float*)d_in[6];
    // d_in[7] = ab2: softmax shift-invariance -> exactly cancels, unused
    const float* fW1      = (const float*)d_in[8];
    const float* fb1      = (const float*)d_in[9];
    const float* fW2      = (const float*)d_in[10];
    const float* fb2      = (const float*)d_in[11];
    const float* fW3      = (const float*)d_in[12];
    const float* fb3      = (const float*)d_in[13];

    const size_t embh_bytes = (size_t)NV * ND * sizeof(bf16_t);   // 12.8 MB
    const size_t comb_bytes = (size_t)NB * 192 * sizeof(float);   // 3.1 MB
    const bool   use_bt     = ws_size >= embh_bytes + comb_bytes;

    if (use_bt) {
        bf16_t* embh = (bf16_t*)d_ws;
        float*  comb = (float*)((char*)d_ws + embh_bytes);
        din_cvt<<<(NV * ND) / (256 * 8), 256, 0, stream>>>(emb, embh);
        din_kernel1<true><<<NB / 4, 256, 0, stream>>>(item_ids, history, hist_len, emb,
                                                      embh, aW1, ab1, aW2, comb);
        din_kernel2<<<NB / 4, 256, 0, stream>>>(comb, fW1, fb1, fW2, fb2, fW3, fb3,
                                                (float*)d_out);
    } else {
        float* comb = (float*)d_ws;
        din_kernel1<false><<<NB / 4, 256, 0, stream>>>(item_ids, history, hist_len, emb,
                                                       (const bf16_t*)nullptr, aW1, ab1, aW2, comb);
        din_kernel2<<<NB / 4, 256, 0, stream>>>(comb, fW1, fb1, fW2, fb2, fW3, fb3,
                                                (float*)d_out);
    }
}

// Round 6
// 170.404 us; speedup vs baseline: 2.5749x; 2.5749x over previous
//
#include <hip/hip_runtime.h>
#include <hip/hip_bf16.h>

#define NV 100000
#define ND 64
#define NB 4096
#define NL 200

typedef __bf16 bf16_t;
typedef __bf16 bf16x8 __attribute__((ext_vector_type(8)));
typedef __bf16 bf16x4 __attribute__((ext_vector_type(4)));
typedef float  f32x4  __attribute__((ext_vector_type(4)));

// f32 table -> bf16 table in ws. 800000 threads x 8 elems = 6.4M exactly.
__global__ __launch_bounds__(256)
void din_cvt(const float* __restrict__ emb, bf16_t* __restrict__ embh)
{
    const long base = ((long)blockIdx.x * 256 + threadIdx.x) * 8;
    f32x4 a0 = *(const f32x4*)(emb + base);
    f32x4 a1 = *(const f32x4*)(emb + base + 4);
    bf16x8 o;
    #pragma unroll
    for (int i = 0; i < 4; ++i) { o[i] = (bf16_t)a0[i]; o[i + 4] = (bf16_t)a1[i]; }
    *(bf16x8*)(embh + base) = o;
}

// Rows stored swizzled: 16B chunk c of row l lives at chunk position c^(l&7).
// Gives conflict-free b128 LDS reads at stride 64 (no padding).
template <bool BT>
__global__ __launch_bounds__(256, 4)
void din_kernel1(const int* __restrict__ item_ids,
                 const int* __restrict__ history,
                 const int* __restrict__ hist_len,
                 const float* __restrict__ emb,
                 const bf16_t* __restrict__ embh,
                 const float* __restrict__ aW1,
                 const float* __restrict__ ab1,
                 const float* __restrict__ aW2,
                 float* __restrict__ comb_ws)
{
    __shared__ __align__(16) bf16_t histA[208 * 64];   // swizzled rows
    __shared__ __align__(16) bf16_t wbT[64 * 64];      // swizzled rows: wbT[n][k]
    __shared__ __align__(16) float sc_w[208];
    __shared__ float pp[256];
    __shared__ float tgt[64];
    __shared__ float cb[64];
    __shared__ float pooled[64];
    __shared__ float red[8];

    const int b    = blockIdx.x;
    const int tid  = threadIdx.x;
    const int item = item_ids[b];
    const int len  = hist_len[b];                      // [1, 200]
    const int wave = tid >> 6, lane = tid & 63;
    const int col  = lane & 15, quad = lane >> 4;
    const int c7   = col & 7;

    if (tid < 64) tgt[tid] = emb[(long)item * ND + tid];

    // ---- phase 1: gather history rows -> swizzled LDS, ONE 16B inst per row-slice ----
    if constexpr (BT) {
        const int seg = tid & 7;       // 16B piece of a 128B row
        const int rl  = tid >> 3;      // 32 rows per pass
        #pragma unroll
        for (int pass = 0; pass < 7; ++pass) {
            const int l = pass * 32 + rl;              // 0..223
            if (l < 208) {
                const int lc  = l < NL ? l : NL - 1;
                const int idx = history[b * NL + lc];
                bf16x8 v = (bf16x8)(bf16_t)0.f;
                if (l < len) v = *(const bf16x8*)(embh + (long)idx * ND + seg * 8);
                *(bf16x8*)&histA[l * 64 + ((seg ^ (l & 7)) * 8)] = v;
            }
        }
    } else {
        const int seg = tid & 15;      // 16B piece of a 256B f32 row
        const int rl  = tid >> 4;      // 16 rows per pass
        #pragma unroll
        for (int pass = 0; pass < 13; ++pass) {
            const int l = pass * 16 + rl;
            if (l < 208) {
                const int lc  = l < NL ? l : NL - 1;
                const int idx = history[b * NL + lc];
                bf16x4 v = (bf16x4)(bf16_t)0.f;
                if (l < len) {
                    f32x4 a = *(const f32x4*)(emb + (long)idx * ND + seg * 4);
                    #pragma unroll
                    for (int i = 0; i < 4; ++i) v[i] = (bf16_t)a[i];
                }
                *(bf16x4*)&histA[l * 64 + (((seg >> 1) ^ (l & 7)) * 8) + (seg & 1) * 4] = v;
            }
        }
    }

    // ---- phase 2: build wbT[n][k] = aW1[k][n] + t[k]*aW1[128+k][n] (coalesced), cb partials ----
    {
        const int n  = tid & 63;
        const int kp = tid >> 6;                       // k quarter: [kp*16, kp*16+16)
        const float* tq = emb + (long)item * ND + kp * 16;
        f32x4 t0 = *(const f32x4*)(tq);
        f32x4 t1 = *(const f32x4*)(tq + 4);
        f32x4 t2 = *(const f32x4*)(tq + 8);
        f32x4 t3 = *(const f32x4*)(tq + 12);
        float tk[16];
        #pragma unroll
        for (int i = 0; i < 4; ++i) {
            tk[i] = t0[i]; tk[4 + i] = t1[i]; tk[8 + i] = t2[i]; tk[12 + i] = t3[i];
        }
        float csum = 0.f;
        #pragma unroll
        for (int i = 0; i < 16; ++i) {
            const int k = kp * 16 + i;
            float wa = aW1[k * 64 + n];                // coalesced across n
            float wc = aW1[(128 + k) * 64 + n];
            float wb = aW1[(64 + k) * 64 + n];
            wbT[n * 64 + (((k >> 3) ^ (n & 7)) * 8) + (k & 7)] = (bf16_t)(wa + tk[i] * wc);
            csum += tk[i] * wb;
        }
        pp[tid] = csum;                                // pp[kp*64 + n]
    }

    __syncthreads();   // histA + wbT + pp visible

    if (tid < 64) cb[tid] = ab1[tid] + pp[tid] + pp[64 + tid] + pp[128 + tid] + pp[192 + tid];

    // B-frags from swizzled LDS: row n = nt*16+col, k-chunk kb*4+quad
    bf16x8 bfrag[4][2];
    #pragma unroll
    for (int nt = 0; nt < 4; ++nt)
        #pragma unroll
        for (int kb = 0; kb < 2; ++kb)
            bfrag[nt][kb] = *(const bf16x8*)&wbT[(nt * 16 + col) * 64 + (((kb * 4 + quad) ^ c7) * 8)];
    float a2vals[4];
    #pragma unroll
    for (int nt = 0; nt < 4; ++nt) a2vals[nt] = aW2[nt * 16 + col];

    __syncthreads();   // cb visible
    float cvals[4];
    #pragma unroll
    for (int nt = 0; nt < 4; ++nt) cvals[nt] = cb[nt * 16 + col];

    // ---- phase 3: scores via MFMA, A-frags from swizzled LDS ----
    for (int mt = wave; mt < 13; mt += 4) {
        const bf16_t* arow = &histA[(mt * 16 + col) * 64];
        bf16x8 af0 = *(const bf16x8*)(arow + ((quad ^ c7) * 8));
        bf16x8 af1 = *(const bf16x8*)(arow + (((4 + quad) ^ c7) * 8));
        float sc[4] = {0.f, 0.f, 0.f, 0.f};
        #pragma unroll
        for (int nt = 0; nt < 4; ++nt) {
            f32x4 acc = {0.f, 0.f, 0.f, 0.f};
            acc = __builtin_amdgcn_mfma_f32_16x16x32_bf16(af0, bfrag[nt][0], acc, 0, 0, 0);
            acc = __builtin_amdgcn_mfma_f32_16x16x32_bf16(af1, bfrag[nt][1], acc, 0, 0, 0);
            #pragma unroll
            for (int i = 0; i < 4; ++i) {
                float h = acc[i] + cvals[nt];
                h = h > 0.f ? h : 0.f;
                sc[i] += h * a2vals[nt];
            }
        }
        #pragma unroll
        for (int off = 1; off < 16; off <<= 1)
            #pragma unroll
            for (int i = 0; i < 4; ++i) sc[i] += __shfl_xor(sc[i], off, 64);
        if (col == 0) {
            f32x4 outv = {sc[0], sc[1], sc[2], sc[3]};   // rows quad*4+0..3
            *(f32x4*)&sc_w[mt * 16 + quad * 4] = outv;
        }
    }
    __syncthreads();

    // ---- phase 4: softmax over exactly L=200 ----
    {
        float s = (tid < NL) ? sc_w[tid] : -1e30f;
        float m = s;
        #pragma unroll
        for (int off = 32; off > 0; off >>= 1) m = fmaxf(m, __shfl_xor(m, off, 64));
        if (lane == 0) red[wave] = m;
        __syncthreads();
        m = fmaxf(fmaxf(red[0], red[1]), fmaxf(red[2], red[3]));
        float e = (tid < NL) ? __expf(s - m) : 0.f;
        float ssum = e;
        #pragma unroll
        for (int off = 32; off > 0; off >>= 1) ssum += __shfl_xor(ssum, off, 64);
        if (lane == 0) red[4 + wave] = ssum;
        __syncthreads();
        float tot = red[4] + red[5] + red[6] + red[7];
        if (tid < NL) sc_w[tid] = e / tot;
    }
    __syncthreads();

    // ---- phase 5: pooled from swizzled LDS (rows >= len already zero) ----
    {
        float acc = 0.f;
        for (int l = wave; l < NL; l += 4) {
            const int pos = l * 64 + (((lane >> 3) ^ (l & 7)) * 8) + (lane & 7);
            acc += sc_w[l] * (float)histA[pos];
        }
        pp[wave * 64 + lane] = acc;
    }
    __syncthreads();
    if (tid < 64) pooled[tid] = pp[tid] + pp[64 + tid] + pp[128 + tid] + pp[192 + tid];
    __syncthreads();

    // ---- phase 6: comb = [tgt, pooled, pooled - tgt] ----
    if (tid < 192) {
        float v;
        if (tid < 64)       v = tgt[tid];
        else if (tid < 128) v = pooled[tid - 64];
        else                v = pooled[tid - 128] - tgt[tid - 128];
        comb_ws[(long)b * 192 + tid] = v;
    }
}

__global__ __launch_bounds__(256)
void din_kernel2(const float* __restrict__ comb,
                 const float* __restrict__ fW1, const float* __restrict__ fb1,
                 const float* __restrict__ fW2, const float* __restrict__ fb2,
                 const float* __restrict__ fW3, const float* __restrict__ fb3,
                 float* __restrict__ out)
{
    __shared__ float combs[4 * 192];
    __shared__ float z1s[4 * 128];
    const int tid = threadIdx.x;
    const int rb  = blockIdx.x * 4;

    for (int i = tid; i < 4 * 192; i += 256) combs[i] = comb[(long)rb * 192 + i];
    __syncthreads();

    {
        const int j  = tid & 127;
        const int r0 = (tid >> 7) * 2, r1 = r0 + 1;
        float a0 = fb1[j], a1 = a0;
        #pragma unroll 4
        for (int i = 0; i < 192; ++i) {
            float w = fW1[i * 128 + j];
            a0 += combs[r0 * 192 + i] * w;
            a1 += combs[r1 * 192 + i] * w;
        }
        z1s[r0 * 128 + j] = fmaxf(a0, 0.f);
        z1s[r1 * 128 + j] = fmaxf(a1, 0.f);
    }
    __syncthreads();

    {
        const int j2 = tid & 63;
        const int r2 = tid >> 6;
        float acc = fb2[j2];
        #pragma unroll 4
        for (int i = 0; i < 128; ++i)
            acc += z1s[r2 * 128 + i] * fW2[i * 64 + j2];
        float s = fmaxf(acc, 0.f) * fW3[j2];
        #pragma unroll
        for (int off = 1; off < 64; off <<= 1) s += __shfl_xor(s, off, 64);
        if (j2 == 0) out[rb + r2] = 1.f / (1.f + __expf(-(s + fb3[0])));
    }
}

extern "C" void kernel_launch(void* const* d_in, const int* in_sizes, int n_in,
                              void* d_out, int out_size, void* d_ws, size_t ws_size,
                              hipStream_t stream) {
    const int*   item_ids = (const int*)d_in[0];
    const int*   history  = (const int*)d_in[1];
    const int*   hist_len = (const int*)d_in[2];
    const float* emb      = (const float*)d_in[3];
    const float* aW1      = (const float*)d_in[4];
    const float* ab1      = (const float*)d_in[5];
    const float* aW2      = (const float*)d_in[6];
    // d_in[7] = ab2: softmax shift-invariance -> exactly cancels, unused
    const float* fW1      = (const float*)d_in[8];
    const float* fb1      = (const float*)d_in[9];
    const float* fW2      = (const float*)d_in[10];
    const float* fb2      = (const float*)d_in[11];
    const float* fW3      = (const float*)d_in[12];
    const float* fb3      = (const float*)d_in[13];

    const size_t embh_bytes = (size_t)NV * ND * sizeof(bf16_t);   // 12.8 MB
    const size_t comb_bytes = (size_t)NB * 192 * sizeof(float);   // 3.1 MB
    const bool   use_bt     = ws_size >= embh_bytes + comb_bytes;

    if (use_bt) {
        bf16_t* embh = (bf16_t*)d_ws;
        float*  comb = (float*)((char*)d_ws + embh_bytes);
        din_cvt<<<(NV * ND) / (256 * 8), 256, 0, stream>>>(emb, embh);
        din_kernel1<true><<<NB, 256, 0, stream>>>(item_ids, history, hist_len, emb,
                                                  embh, aW1, ab1, aW2, comb);
        din_kernel2<<<NB / 4, 256, 0, stream>>>(comb, fW1, fb1, fW2, fb2, fW3, fb3,
                                                (float*)d_out);
    } else {
        float* comb = (float*)d_ws;
        din_kernel1<false><<<NB, 256, 0, stream>>>(item_ids, history, hist_len, emb,
                                                   (const bf16_t*)nullptr, aW1, ab1, aW2, comb);
        din_kernel2<<<NB / 4, 256, 0, stream>>>(comb, fW1, fb1, fW2, fb2, fW3, fb3,
                                                (float*)d_out);
    }
}